// Round 1
// baseline (666.382 us; speedup 1.0000x reference)
//
#include <hip/hip_runtime.h>

#define NN 200000
#define DD 128
#define NHH 8
#define HD 16
#define BB 32
#define SS 512
#define QKV_LD 384

// ---------------------------------------------------------------------------
// K1: fused tree-path-sum + gather.
// x[row,:] = sum_{a on path root..branch_idx[row]} feats[a,:]  (0 if idx==N)
// parent(i) = (i-1)>>1, so no level arrays needed; <=18 ancestors.
// One block per row, 128 threads = one feature element each (coalesced 512B
// row reads, upper tree levels are L2/L3-resident across blocks).
// ---------------------------------------------------------------------------
__global__ __launch_bounds__(DD) void k_gather(const float* __restrict__ feats,
                                               const int* __restrict__ bidx,
                                               float* __restrict__ x) {
    int row = blockIdx.x;            // 0..B*S-1
    int d = threadIdx.x;             // 0..127
    int idx = bidx[row];
    float acc = 0.f;
    if (idx >= 0 && idx < NN) {
        int v = idx;
        while (true) {
            acc += feats[(long)v * DD + d];
            if (v == 0) break;
            v = (v - 1) >> 1;
        }
    }
    x[(long)row * DD + d] = acc;
}

// ---------------------------------------------------------------------------
// K2: qkv = x @ Win^T + bin.   [16384,128] @ [384,128]^T -> [16384,384]
// 32 rows per block staged in LDS; weight reads are L2-resident (196KB).
// ---------------------------------------------------------------------------
__global__ __launch_bounds__(256) void k_qkv(const float* __restrict__ x,
                                             const float* __restrict__ Win,
                                             const float* __restrict__ bin,
                                             float* __restrict__ qkv) {
    __shared__ float xt[32][DD];
    int row0 = blockIdx.x * 32;
    int t = threadIdx.x;
    for (int i = t; i < 32 * DD; i += 256)
        xt[i / DD][i % DD] = x[(long)row0 * DD + i];
    __syncthreads();
    for (int i = t; i < 32 * QKV_LD; i += 256) {
        int r = i / QKV_LD, j = i % QKV_LD;
        const float* w = Win + (long)j * DD;
        float s = 0.f;
        #pragma unroll 8
        for (int c = 0; c < DD; ++c) s += xt[r][c] * w[c];
        qkv[((long)(row0 + r)) * QKV_LD + j] = s + bin[j];
    }
}

// ---------------------------------------------------------------------------
// K3: per-(b,h) attention, K/V staged in LDS (64KB), online softmax.
// Emits only the query-summed head output: t[b, h*16+d] = sum_q o[b,q,h,d].
// Additive mask: +1.0 where (q valid && k valid), else +0. Softmax over all
// 512 keys (pads have k=v=0 exactly, matching the reference).
// ---------------------------------------------------------------------------
__global__ __launch_bounds__(256) void k_attn(const float* __restrict__ qkv,
                                              const int* __restrict__ lengths,
                                              float* __restrict__ tout) {
    int b = blockIdx.x / NHH;
    int h = blockIdx.x % NHH;
    int t = threadIdx.x;
    __shared__ float Ks[SS][HD];
    __shared__ float Vs[SS][HD];
    int len = lengths[b];
    const float* base = qkv + (long)b * SS * QKV_LD;
    for (int i = t; i < SS * HD; i += 256) {
        int r = i / HD, d = i % HD;
        Ks[r][d] = base[(long)r * QKV_LD + DD + h * HD + d];
        Vs[r][d] = base[(long)r * QKV_LD + 2 * DD + h * HD + d];
    }
    __syncthreads();

    float osum[HD];
    #pragma unroll
    for (int d = 0; d < HD; ++d) osum[d] = 0.f;

    for (int qi = t; qi < SS; qi += 256) {   // 2 queries per thread
        float qr[HD];
        #pragma unroll
        for (int d = 0; d < HD; ++d) qr[d] = base[(long)qi * QKV_LD + h * HD + d];
        bool vq = qi < len;
        float m = -1e30f, l = 0.f;
        float acc[HD];
        #pragma unroll
        for (int d = 0; d < HD; ++d) acc[d] = 0.f;
        for (int kk = 0; kk < SS; ++kk) {
            float s = 0.f;
            #pragma unroll
            for (int d = 0; d < HD; ++d) s += qr[d] * Ks[kk][d];
            s *= 0.25f;
            if (vq && kk < len) s += 1.0f;
            float mn = fmaxf(m, s);
            float sc = __expf(m - mn);
            float p  = __expf(s - mn);
            l = l * sc + p;
            #pragma unroll
            for (int d = 0; d < HD; ++d) acc[d] = acc[d] * sc + p * Vs[kk][d];
            m = mn;
        }
        float inv = 1.f / l;
        #pragma unroll
        for (int d = 0; d < HD; ++d) osum[d] += acc[d] * inv;
    }

    // reduce osum[16] across 256 threads: wave shuffle then LDS across 4 waves
    __shared__ float red[4][HD];
    int lane = t & 63, wave = t >> 6;
    #pragma unroll
    for (int d = 0; d < HD; ++d) {
        float v = osum[d];
        for (int off = 32; off >= 1; off >>= 1) v += __shfl_down(v, off, 64);
        if (lane == 0) red[wave][d] = v;
        osum[d] = v;
    }
    __syncthreads();
    if (t < HD) {
        float v = red[0][t] + red[1][t] + red[2][t] + red[3][t];
        tout[b * DD + h * HD + t] = v;
    }
}

// ---------------------------------------------------------------------------
// K4: out[b,d] = sum_c t[b,c] * Wout[d,c] + S * bout[d]
// ---------------------------------------------------------------------------
__global__ __launch_bounds__(DD) void k_out(const float* __restrict__ tsum,
                                            const float* __restrict__ Wout,
                                            const float* __restrict__ bout,
                                            float* __restrict__ out) {
    int b = blockIdx.x;
    int d = threadIdx.x;
    __shared__ float tr[DD];
    tr[d] = tsum[b * DD + d];
    __syncthreads();
    float s = (float)SS * bout[d];
    #pragma unroll 8
    for (int c = 0; c < DD; ++c) s += tr[c] * Wout[d * DD + c];
    out[b * DD + d] = s;
}

extern "C" void kernel_launch(void* const* d_in, const int* in_sizes, int n_in,
                              void* d_out, int out_size, void* d_ws, size_t ws_size,
                              hipStream_t stream) {
    const float* feats = (const float*)d_in[0];
    const float* Win   = (const float*)d_in[1];
    const float* bin   = (const float*)d_in[2];
    const float* Wout  = (const float*)d_in[3];
    const float* bout  = (const float*)d_in[4];
    // d_in[5], d_in[6] (levels_child/parent) unused: parent(i) = (i-1)>>1
    const int* bidx    = (const int*)d_in[7];
    const int* lengths = (const int*)d_in[8];
    float* out = (float*)d_out;

    char* ws = (char*)d_ws;
    float* x    = (float*)ws;                                   // 8 MB
    float* qkv  = (float*)(ws + (size_t)BB * SS * DD * 4);      // 24 MB
    float* tsum = (float*)(ws + (size_t)BB * SS * DD * 4
                              + (size_t)BB * SS * QKV_LD * 4);  // 16 KB

    k_gather<<<BB * SS, DD, 0, stream>>>(feats, bidx, x);
    k_qkv<<<BB * SS / 32, 256, 0, stream>>>(x, Win, bin, qkv);
    k_attn<<<BB * NHH, 256, 0, stream>>>(qkv, lengths, tsum);
    k_out<<<BB, DD, 0, stream>>>(tsum, Wout, bout, out);
}

// Round 2
// 329.425 us; speedup vs baseline: 2.0229x; 2.0229x over previous
//
#include <hip/hip_runtime.h>

#define NN 200000
#define DD 128
#define NHH 8
#define HD 16
#define BB 32
#define SS 512
#define QKV_LD 384

// ---------------------------------------------------------------------------
// K1: fused tree-path-sum + gather.
// x[row,:] = sum over ancestors of branch_idx[row] of feats[a,:] (0 if idx==N)
// parent(i) = (i-1)>>1; <=18 ancestors. One block per row, 128 threads.
// ---------------------------------------------------------------------------
__global__ __launch_bounds__(DD) void k_gather(const float* __restrict__ feats,
                                               const int* __restrict__ bidx,
                                               float* __restrict__ x) {
    int row = blockIdx.x;
    int d = threadIdx.x;
    int idx = bidx[row];
    float acc = 0.f;
    if (idx >= 0 && idx < NN) {
        int v = idx;
        while (true) {
            acc += feats[(long)v * DD + d];
            if (v == 0) break;
            v = (v - 1) >> 1;
        }
    }
    x[(long)row * DD + d] = acc;
}

// ---------------------------------------------------------------------------
// K2: qkv = x @ Win^T + bin.  [16384,128] @ [384,128]^T -> [16384,384]
// Register-blocked tile GEMM: 64x64 tile per block, 256 threads, 4x4 outputs
// per thread, K=128. LDS tiles stored as float4 chunks with an XOR swizzle
// (chunk ^ (row>>2)&7) so the stride-4-row b128 reads hit distinct bank quads.
// ---------------------------------------------------------------------------
__global__ __launch_bounds__(256) void k_qkv(const float* __restrict__ x,
                                             const float* __restrict__ Win,
                                             const float* __restrict__ bin,
                                             float* __restrict__ qkv) {
    __shared__ float4 Xs[64 * 32];   // 32 KB
    __shared__ float4 Ws[64 * 32];   // 32 KB
    int t = threadIdx.x;
    int rb = blockIdx.x / 6;         // 0..255 row block
    int cb = blockIdx.x % 6;         // 0..5 col block
    long row0 = (long)rb * 64;
    int  col0 = cb * 64;
    const float4* xg = (const float4*)(x + row0 * DD);
    const float4* wg = (const float4*)(Win + (long)col0 * DD);
    #pragma unroll
    for (int n = 0; n < 8; ++n) {
        int idx = n * 256 + t;               // 0..2047 float4s (64 rows x 32)
        int r = idx >> 5, c4 = idx & 31;
        int p = r * 32 + (c4 ^ ((r >> 2) & 7));
        Xs[p] = xg[idx];
        Ws[p] = wg[idx];
    }
    __syncthreads();
    int ty = t >> 4, tx = t & 15;            // 16x16 thread grid
    float acc[4][4] = {};
    #pragma unroll
    for (int k4 = 0; k4 < 32; ++k4) {
        float4 xa[4], wb[4];
        #pragma unroll
        for (int i = 0; i < 4; ++i) xa[i] = Xs[(ty * 4 + i) * 32 + (k4 ^ (ty & 7))];
        #pragma unroll
        for (int j = 0; j < 4; ++j) wb[j] = Ws[(tx * 4 + j) * 32 + (k4 ^ (tx & 7))];
        #pragma unroll
        for (int i = 0; i < 4; ++i)
            #pragma unroll
            for (int j = 0; j < 4; ++j)
                acc[i][j] += xa[i].x * wb[j].x + xa[i].y * wb[j].y
                           + xa[i].z * wb[j].z + xa[i].w * wb[j].w;
    }
    #pragma unroll
    for (int i = 0; i < 4; ++i) {
        long r = row0 + ty * 4 + i;
        int c = col0 + tx * 4;
        float4 bv = *(const float4*)(bin + c);
        float4 o;
        o.x = acc[i][0] + bv.x; o.y = acc[i][1] + bv.y;
        o.z = acc[i][2] + bv.z; o.w = acc[i][3] + bv.w;
        *(float4*)(qkv + r * QKV_LD + c) = o;
    }
}

// ---------------------------------------------------------------------------
// K3: per-(b,h) attention, K/V staged in LDS, online softmax with 4-key
// batching (one rescale per group), float4 LDS reads, 2 queries per thread.
// Emits query-summed head output t[b, h*16+d] = sum_q o[b,q,h,d].
// ---------------------------------------------------------------------------
__global__ __launch_bounds__(256) void k_attn(const float* __restrict__ qkv,
                                              const int* __restrict__ lengths,
                                              float* __restrict__ tout) {
    int b = blockIdx.x >> 3;
    int h = blockIdx.x & 7;
    int t = threadIdx.x;
    __shared__ float4 Ks[SS * 4];   // 32 KB, row r = Ks[r*4 .. r*4+3]
    __shared__ float4 Vs[SS * 4];   // 32 KB
    __shared__ float red[4][HD];
    int len = lengths[b];
    const float* base = qkv + (long)b * SS * QKV_LD;
    #pragma unroll
    for (int n = 0; n < 8; ++n) {
        int idx = n * 256 + t;               // 0..2047
        int r = idx >> 2, c4 = idx & 3;
        Ks[idx] = *(const float4*)(base + (long)r * QKV_LD + DD + h * HD + c4 * 4);
        Vs[idx] = *(const float4*)(base + (long)r * QKV_LD + 2 * DD + h * HD + c4 * 4);
    }
    __syncthreads();

    // load 2 queries
    float qr[2][HD];
    bool vq[2];
    #pragma unroll
    for (int q = 0; q < 2; ++q) {
        int qi = t + q * 256;
        vq[q] = qi < len;
        #pragma unroll
        for (int c4 = 0; c4 < 4; ++c4) {
            float4 v = *(const float4*)(base + (long)qi * QKV_LD + h * HD + c4 * 4);
            qr[q][c4 * 4 + 0] = v.x; qr[q][c4 * 4 + 1] = v.y;
            qr[q][c4 * 4 + 2] = v.z; qr[q][c4 * 4 + 3] = v.w;
        }
    }

    float m[2] = {-1e30f, -1e30f}, l[2] = {0.f, 0.f};
    float acc[2][HD] = {};

    for (int kk = 0; kk < SS; kk += 4) {
        float4 kb[4][4];
        #pragma unroll
        for (int u = 0; u < 4; ++u)
            #pragma unroll
            for (int c = 0; c < 4; ++c) kb[u][c] = Ks[(kk + u) * 4 + c];
        float s[2][4];
        #pragma unroll
        for (int q = 0; q < 2; ++q) {
            #pragma unroll
            for (int u = 0; u < 4; ++u) {
                float d0 = qr[q][0]  * kb[u][0].x + qr[q][1]  * kb[u][0].y
                         + qr[q][2]  * kb[u][0].z + qr[q][3]  * kb[u][0].w;
                float d1 = qr[q][4]  * kb[u][1].x + qr[q][5]  * kb[u][1].y
                         + qr[q][6]  * kb[u][1].z + qr[q][7]  * kb[u][1].w;
                float d2 = qr[q][8]  * kb[u][2].x + qr[q][9]  * kb[u][2].y
                         + qr[q][10] * kb[u][2].z + qr[q][11] * kb[u][2].w;
                float d3 = qr[q][12] * kb[u][3].x + qr[q][13] * kb[u][3].y
                         + qr[q][14] * kb[u][3].z + qr[q][15] * kb[u][3].w;
                float mk = (vq[q] && (kk + u) < len) ? 1.0f : 0.0f;
                s[q][u] = (d0 + d1 + d2 + d3) * 0.25f + mk;
            }
        }
        float4 vb[4][4];
        #pragma unroll
        for (int u = 0; u < 4; ++u)
            #pragma unroll
            for (int c = 0; c < 4; ++c) vb[u][c] = Vs[(kk + u) * 4 + c];
        #pragma unroll
        for (int q = 0; q < 2; ++q) {
            float mn = fmaxf(fmaxf(fmaxf(s[q][0], s[q][1]), fmaxf(s[q][2], s[q][3])), m[q]);
            float sc = __expf(m[q] - mn);
            m[q] = mn;
            float p0 = __expf(s[q][0] - mn);
            float p1 = __expf(s[q][1] - mn);
            float p2 = __expf(s[q][2] - mn);
            float p3 = __expf(s[q][3] - mn);
            l[q] = l[q] * sc + (p0 + p1) + (p2 + p3);
            #pragma unroll
            for (int c = 0; c < 4; ++c) {
                acc[q][c * 4 + 0] = acc[q][c * 4 + 0] * sc + p0 * vb[0][c].x + p1 * vb[1][c].x + p2 * vb[2][c].x + p3 * vb[3][c].x;
                acc[q][c * 4 + 1] = acc[q][c * 4 + 1] * sc + p0 * vb[0][c].y + p1 * vb[1][c].y + p2 * vb[2][c].y + p3 * vb[3][c].y;
                acc[q][c * 4 + 2] = acc[q][c * 4 + 2] * sc + p0 * vb[0][c].z + p1 * vb[1][c].z + p2 * vb[2][c].z + p3 * vb[3][c].z;
                acc[q][c * 4 + 3] = acc[q][c * 4 + 3] * sc + p0 * vb[0][c].w + p1 * vb[1][c].w + p2 * vb[2][c].w + p3 * vb[3][c].w;
            }
        }
    }

    float osum[HD];
    float inv0 = 1.f / l[0], inv1 = 1.f / l[1];
    #pragma unroll
    for (int d = 0; d < HD; ++d) osum[d] = acc[0][d] * inv0 + acc[1][d] * inv1;

    int lane = t & 63, wave = t >> 6;
    #pragma unroll
    for (int d = 0; d < HD; ++d) {
        float v = osum[d];
        for (int off = 32; off >= 1; off >>= 1) v += __shfl_down(v, off, 64);
        if (lane == 0) red[wave][d] = v;
    }
    __syncthreads();
    if (t < HD) {
        float v = red[0][t] + red[1][t] + red[2][t] + red[3][t];
        tout[b * DD + h * HD + t] = v;
    }
}

// ---------------------------------------------------------------------------
// K4: out[b,d] = sum_c t[b,c] * Wout[d,c] + S * bout[d]
// ---------------------------------------------------------------------------
__global__ __launch_bounds__(DD) void k_out(const float* __restrict__ tsum,
                                            const float* __restrict__ Wout,
                                            const float* __restrict__ bout,
                                            float* __restrict__ out) {
    int b = blockIdx.x;
    int d = threadIdx.x;
    __shared__ float tr[DD];
    tr[d] = tsum[b * DD + d];
    __syncthreads();
    float s = (float)SS * bout[d];
    #pragma unroll 8
    for (int c = 0; c < DD; ++c) s += tr[c] * Wout[d * DD + c];
    out[b * DD + d] = s;
}

extern "C" void kernel_launch(void* const* d_in, const int* in_sizes, int n_in,
                              void* d_out, int out_size, void* d_ws, size_t ws_size,
                              hipStream_t stream) {
    const float* feats = (const float*)d_in[0];
    const float* Win   = (const float*)d_in[1];
    const float* bin   = (const float*)d_in[2];
    const float* Wout  = (const float*)d_in[3];
    const float* bout  = (const float*)d_in[4];
    const int* bidx    = (const int*)d_in[7];
    const int* lengths = (const int*)d_in[8];
    float* out = (float*)d_out;

    char* ws = (char*)d_ws;
    float* x    = (float*)ws;                                   // 8 MB
    float* qkv  = (float*)(ws + (size_t)BB * SS * DD * 4);      // 24 MB
    float* tsum = (float*)(ws + (size_t)BB * SS * DD * 4
                              + (size_t)BB * SS * QKV_LD * 4);  // 16 KB

    k_gather<<<BB * SS, DD, 0, stream>>>(feats, bidx, x);
    k_qkv<<<(BB * SS / 64) * 6, 256, 0, stream>>>(x, Win, bin, qkv);
    k_attn<<<BB * NHH, 256, 0, stream>>>(qkv, lengths, tsum);
    k_out<<<BB, DD, 0, stream>>>(tsum, Wout, bout, out);
}

// Round 3
// 324.994 us; speedup vs baseline: 2.0504x; 1.0136x over previous
//
#include <hip/hip_runtime.h>

#define NN 200000
#define DD 128
#define NHH 8
#define HD 16
#define BB 32
#define SS 512
#define QKV_LD 384

// ---------------------------------------------------------------------------
// K1: fused tree-path-sum + gather, latency-optimized.
// 8 rows per 256-thread block; 32 threads (float4 lanes) per row.
// Ancestor chain is pure arithmetic -> precompute 6 indices per batch, issue
// 6 independent float4 loads, one drain per batch (3 batches cover depth 18).
// ---------------------------------------------------------------------------
__global__ __launch_bounds__(256) void k_gather(const float* __restrict__ feats,
                                                const int* __restrict__ bidx,
                                                float* __restrict__ x) {
    int t = threadIdx.x;
    int r = t >> 5;                  // 0..7 row within block
    int c4 = t & 31;                 // float4 column
    long row = (long)blockIdx.x * 8 + r;
    int idx = bidx[row];
    int v = (idx >= 0 && idx < NN) ? idx : NN;
    float4 acc = make_float4(0.f, 0.f, 0.f, 0.f);
    const float4* f4 = (const float4*)feats;
    #pragma unroll
    for (int batch = 0; batch < 3; ++batch) {
        int a[6];
        #pragma unroll
        for (int k = 0; k < 6; ++k) {
            a[k] = v;
            v = (v == 0 || v >= NN) ? NN : (v - 1) >> 1;
        }
        float4 val[6];
        #pragma unroll
        for (int k = 0; k < 6; ++k) {
            if (a[k] < NN) val[k] = f4[(long)a[k] * 32 + c4];
            else           val[k] = make_float4(0.f, 0.f, 0.f, 0.f);
        }
        #pragma unroll
        for (int k = 0; k < 6; ++k) {
            acc.x += val[k].x; acc.y += val[k].y;
            acc.z += val[k].z; acc.w += val[k].w;
        }
    }
    ((float4*)x)[row * 32 + c4] = acc;
}

// ---------------------------------------------------------------------------
// K2: qkv = x @ Win^T + bin.  64x64 tile per block, 4x4 outputs/thread.
// ---------------------------------------------------------------------------
__global__ __launch_bounds__(256) void k_qkv(const float* __restrict__ x,
                                             const float* __restrict__ Win,
                                             const float* __restrict__ bin,
                                             float* __restrict__ qkv) {
    __shared__ float4 Xs[64 * 32];
    __shared__ float4 Ws[64 * 32];
    int t = threadIdx.x;
    int rb = blockIdx.x / 6;
    int cb = blockIdx.x % 6;
    long row0 = (long)rb * 64;
    int  col0 = cb * 64;
    const float4* xg = (const float4*)(x + row0 * DD);
    const float4* wg = (const float4*)(Win + (long)col0 * DD);
    #pragma unroll
    for (int n = 0; n < 8; ++n) {
        int idx = n * 256 + t;
        int r = idx >> 5, c4 = idx & 31;
        int p = r * 32 + (c4 ^ ((r >> 2) & 7));
        Xs[p] = xg[idx];
        Ws[p] = wg[idx];
    }
    __syncthreads();
    int ty = t >> 4, tx = t & 15;
    float acc[4][4] = {};
    #pragma unroll
    for (int k4 = 0; k4 < 32; ++k4) {
        float4 xa[4], wb[4];
        #pragma unroll
        for (int i = 0; i < 4; ++i) xa[i] = Xs[(ty * 4 + i) * 32 + (k4 ^ (ty & 7))];
        #pragma unroll
        for (int j = 0; j < 4; ++j) wb[j] = Ws[(tx * 4 + j) * 32 + (k4 ^ (tx & 7))];
        #pragma unroll
        for (int i = 0; i < 4; ++i)
            #pragma unroll
            for (int j = 0; j < 4; ++j)
                acc[i][j] += xa[i].x * wb[j].x + xa[i].y * wb[j].y
                           + xa[i].z * wb[j].z + xa[i].w * wb[j].w;
    }
    #pragma unroll
    for (int i = 0; i < 4; ++i) {
        long r = row0 + ty * 4 + i;
        int c = col0 + tx * 4;
        float4 bv = *(const float4*)(bin + c);
        float4 o;
        o.x = acc[i][0] + bv.x; o.y = acc[i][1] + bv.y;
        o.z = acc[i][2] + bv.z; o.w = acc[i][3] + bv.w;
        *(float4*)(qkv + r * QKV_LD + c) = o;
    }
}

// ---------------------------------------------------------------------------
// K3a: attention pass 1, key-split 2-way. Block = (b,h,half); stages 256
// keys' K/V in LDS (32KB -> 2 blocks/CU), 2 queries/thread over 256 keys,
// online softmax, writes per-query partials (m, l, acc[16]).
// ---------------------------------------------------------------------------
__global__ __launch_bounds__(256) void k_attn_part(const float* __restrict__ qkv,
                                                   const int* __restrict__ lengths,
                                                   float* __restrict__ pacc,
                                                   float* __restrict__ pml) {
    int bh = blockIdx.x >> 1;
    int half = blockIdx.x & 1;
    int b = bh >> 3;
    int h = bh & 7;
    int t = threadIdx.x;
    __shared__ float4 Ks[256 * 4];   // 16 KB
    __shared__ float4 Vs[256 * 4];   // 16 KB
    int len = lengths[b];
    int koff = half * 256;
    int rel = len - koff;            // key kk valid iff kk < rel
    const float* base = qkv + (long)b * SS * QKV_LD;
    const float* kbase = base + (long)koff * QKV_LD;
    #pragma unroll
    for (int n = 0; n < 4; ++n) {
        int idx = n * 256 + t;               // 0..1023
        int r = idx >> 2, c4 = idx & 3;
        Ks[idx] = *(const float4*)(kbase + (long)r * QKV_LD + DD + h * HD + c4 * 4);
        Vs[idx] = *(const float4*)(kbase + (long)r * QKV_LD + 2 * DD + h * HD + c4 * 4);
    }
    __syncthreads();

    float qr[2][HD];
    bool vq[2];
    #pragma unroll
    for (int q = 0; q < 2; ++q) {
        int qi = t + q * 256;
        vq[q] = qi < len;
        #pragma unroll
        for (int c4 = 0; c4 < 4; ++c4) {
            float4 v = *(const float4*)(base + (long)qi * QKV_LD + h * HD + c4 * 4);
            qr[q][c4 * 4 + 0] = v.x; qr[q][c4 * 4 + 1] = v.y;
            qr[q][c4 * 4 + 2] = v.z; qr[q][c4 * 4 + 3] = v.w;
        }
    }

    float m[2] = {-1e30f, -1e30f}, l[2] = {0.f, 0.f};
    float acc[2][HD] = {};

    for (int kk = 0; kk < 256; kk += 4) {
        float4 kb[4][4];
        #pragma unroll
        for (int u = 0; u < 4; ++u)
            #pragma unroll
            for (int c = 0; c < 4; ++c) kb[u][c] = Ks[(kk + u) * 4 + c];
        float s[2][4];
        #pragma unroll
        for (int q = 0; q < 2; ++q) {
            #pragma unroll
            for (int u = 0; u < 4; ++u) {
                float d0 = qr[q][0]  * kb[u][0].x + qr[q][1]  * kb[u][0].y
                         + qr[q][2]  * kb[u][0].z + qr[q][3]  * kb[u][0].w;
                float d1 = qr[q][4]  * kb[u][1].x + qr[q][5]  * kb[u][1].y
                         + qr[q][6]  * kb[u][1].z + qr[q][7]  * kb[u][1].w;
                float d2 = qr[q][8]  * kb[u][2].x + qr[q][9]  * kb[u][2].y
                         + qr[q][10] * kb[u][2].z + qr[q][11] * kb[u][2].w;
                float d3 = qr[q][12] * kb[u][3].x + qr[q][13] * kb[u][3].y
                         + qr[q][14] * kb[u][3].z + qr[q][15] * kb[u][3].w;
                float mk = (vq[q] && (kk + u) < rel) ? 1.0f : 0.0f;
                s[q][u] = (d0 + d1 + d2 + d3) * 0.25f + mk;
            }
        }
        float4 vb[4][4];
        #pragma unroll
        for (int u = 0; u < 4; ++u)
            #pragma unroll
            for (int c = 0; c < 4; ++c) vb[u][c] = Vs[(kk + u) * 4 + c];
        #pragma unroll
        for (int q = 0; q < 2; ++q) {
            float mn = fmaxf(fmaxf(fmaxf(s[q][0], s[q][1]), fmaxf(s[q][2], s[q][3])), m[q]);
            float sc = __expf(m[q] - mn);
            m[q] = mn;
            float p0 = __expf(s[q][0] - mn);
            float p1 = __expf(s[q][1] - mn);
            float p2 = __expf(s[q][2] - mn);
            float p3 = __expf(s[q][3] - mn);
            l[q] = l[q] * sc + (p0 + p1) + (p2 + p3);
            #pragma unroll
            for (int c = 0; c < 4; ++c) {
                acc[q][c * 4 + 0] = acc[q][c * 4 + 0] * sc + p0 * vb[0][c].x + p1 * vb[1][c].x + p2 * vb[2][c].x + p3 * vb[3][c].x;
                acc[q][c * 4 + 1] = acc[q][c * 4 + 1] * sc + p0 * vb[0][c].y + p1 * vb[1][c].y + p2 * vb[2][c].y + p3 * vb[3][c].y;
                acc[q][c * 4 + 2] = acc[q][c * 4 + 2] * sc + p0 * vb[0][c].z + p1 * vb[1][c].z + p2 * vb[2][c].z + p3 * vb[3][c].z;
                acc[q][c * 4 + 3] = acc[q][c * 4 + 3] * sc + p0 * vb[0][c].w + p1 * vb[1][c].w + p2 * vb[2][c].w + p3 * vb[3][c].w;
            }
        }
    }

    long pbase = (long)blockIdx.x * 512;     // [bh][half] major
    #pragma unroll
    for (int q = 0; q < 2; ++q) {
        int qi = t + q * 256;
        float4* pa = (float4*)(pacc + (pbase + qi) * 16);
        #pragma unroll
        for (int c = 0; c < 4; ++c) {
            float4 o;
            o.x = acc[q][c * 4 + 0]; o.y = acc[q][c * 4 + 1];
            o.z = acc[q][c * 4 + 2]; o.w = acc[q][c * 4 + 3];
            pa[c] = o;
        }
        float2* pm = (float2*)(pml + (pbase + qi) * 2);
        *pm = make_float2(m[q], l[q]);
    }
}

// ---------------------------------------------------------------------------
// K3b: combine the two key-halves per query, then sum over queries.
// ---------------------------------------------------------------------------
__global__ __launch_bounds__(256) void k_attn_comb(const float* __restrict__ pacc,
                                                   const float* __restrict__ pml,
                                                   float* __restrict__ tout) {
    int bh = blockIdx.x;
    int t = threadIdx.x;
    __shared__ float red[4][HD];
    float osum[HD] = {};
    #pragma unroll
    for (int q = 0; q < 2; ++q) {
        int qi = t + q * 256;
        long i0 = ((long)bh * 2 + 0) * 512 + qi;
        long i1 = ((long)bh * 2 + 1) * 512 + qi;
        float2 ml0 = *(const float2*)(pml + i0 * 2);
        float2 ml1 = *(const float2*)(pml + i1 * 2);
        float M = fmaxf(ml0.x, ml1.x);
        float w0 = __expf(ml0.x - M);
        float w1 = __expf(ml1.x - M);
        float inv = 1.f / (ml0.y * w0 + ml1.y * w1);
        const float4* a0 = (const float4*)(pacc + i0 * 16);
        const float4* a1 = (const float4*)(pacc + i1 * 16);
        #pragma unroll
        for (int c = 0; c < 4; ++c) {
            float4 v0 = a0[c], v1 = a1[c];
            osum[c * 4 + 0] += (v0.x * w0 + v1.x * w1) * inv;
            osum[c * 4 + 1] += (v0.y * w0 + v1.y * w1) * inv;
            osum[c * 4 + 2] += (v0.z * w0 + v1.z * w1) * inv;
            osum[c * 4 + 3] += (v0.w * w0 + v1.w * w1) * inv;
        }
    }
    int lane = t & 63, wave = t >> 6;
    #pragma unroll
    for (int d = 0; d < HD; ++d) {
        float v = osum[d];
        for (int off = 32; off >= 1; off >>= 1) v += __shfl_down(v, off, 64);
        if (lane == 0) red[wave][d] = v;
    }
    __syncthreads();
    if (t < HD) {
        float v = red[0][t] + red[1][t] + red[2][t] + red[3][t];
        tout[bh * HD + t] = v;
    }
}

// ---------------------------------------------------------------------------
// K4: out[b,d] = sum_c t[b,c] * Wout[d,c] + S * bout[d]
// ---------------------------------------------------------------------------
__global__ __launch_bounds__(DD) void k_out(const float* __restrict__ tsum,
                                            const float* __restrict__ Wout,
                                            const float* __restrict__ bout,
                                            float* __restrict__ out) {
    int b = blockIdx.x;
    int d = threadIdx.x;
    __shared__ float tr[DD];
    tr[d] = tsum[b * DD + d];
    __syncthreads();
    float s = (float)SS * bout[d];
    #pragma unroll 8
    for (int c = 0; c < DD; ++c) s += tr[c] * Wout[d * DD + c];
    out[b * DD + d] = s;
}

extern "C" void kernel_launch(void* const* d_in, const int* in_sizes, int n_in,
                              void* d_out, int out_size, void* d_ws, size_t ws_size,
                              hipStream_t stream) {
    const float* feats = (const float*)d_in[0];
    const float* Win   = (const float*)d_in[1];
    const float* bin   = (const float*)d_in[2];
    const float* Wout  = (const float*)d_in[3];
    const float* bout  = (const float*)d_in[4];
    const int* bidx    = (const int*)d_in[7];
    const int* lengths = (const int*)d_in[8];
    float* out = (float*)d_out;

    char* ws = (char*)d_ws;
    // layout (bytes):
    //   qkv : [0, 25165824)
    //   x   : [25165824, 33554432)        dead after k_qkv
    //   pacc: [25165824, 41943040)        aliases x (written after x is dead)
    //   pml : [41943040, 44040192)
    //   tsum: [44040192, +16KB)
    float* qkv  = (float*)ws;
    float* x    = (float*)(ws + 25165824);
    float* pacc = (float*)(ws + 25165824);
    float* pml  = (float*)(ws + 41943040);
    float* tsum = (float*)(ws + 44040192);

    k_gather<<<BB * SS / 8, 256, 0, stream>>>(feats, bidx, x);
    k_qkv<<<(BB * SS / 64) * 6, 256, 0, stream>>>(x, Win, bin, qkv);
    k_attn_part<<<BB * NHH * 2, 256, 0, stream>>>(qkv, lengths, pacc, pml);
    k_attn_comb<<<BB * NHH, 256, 0, stream>>>(pacc, pml, tsum);
    k_out<<<BB, DD, 0, stream>>>(tsum, Wout, bout, out);
}